// Round 1
// baseline (1901.198 us; speedup 1.0000x reference)
//
#include <hip/hip_runtime.h>
#include <math.h>

#define NROWS 500000
#define DIM 256
#define YDIM 50
#define NLAB 1000

// Pass 1: one wave (64 lanes) per row.
//  - float4 load of the 256-f32 row (1 KB per wave access, fully coalesced)
//  - butterfly-reduce dot(x_i, w1), gate g = sigmoid(dot + b1)
//  - scatter g*x_i into seg_a[label], y_i into ysum[label], 1 into counts[label]
__global__ __launch_bounds__(256) void wlp_accum(
    const float* __restrict__ x, const int* __restrict__ labels,
    const float* __restrict__ y, const float* __restrict__ w1,
    const float* __restrict__ b1,
    float* __restrict__ seg_a, float* __restrict__ ysum,
    float* __restrict__ counts)
{
    const int lane  = threadIdx.x & 63;
    const int wib   = threadIdx.x >> 6;
    const int gwave = blockIdx.x * 4 + wib;
    const int nwv   = gridDim.x * 4;

    const float4 wv  = reinterpret_cast<const float4*>(w1)[lane];
    const float  b1v = b1[0];

    for (int i = gwave; i < NROWS; i += nwv) {
        const float4 xv = reinterpret_cast<const float4*>(x)[i * 64 + lane];
        float p = xv.x * wv.x + xv.y * wv.y + xv.z * wv.z + xv.w * wv.w;
        #pragma unroll
        for (int off = 32; off > 0; off >>= 1) p += __shfl_xor(p, off);
        const float g = 1.0f / (1.0f + __expf(-(p + b1v)));

        const int l = labels[i];
        float* base = seg_a + (size_t)l * DIM + lane * 4;
        atomicAdd(base + 0, g * xv.x);
        atomicAdd(base + 1, g * xv.y);
        atomicAdd(base + 2, g * xv.z);
        atomicAdd(base + 3, g * xv.w);

        if (lane < YDIM)
            atomicAdd(ysum + (size_t)l * YDIM + lane, y[(size_t)i * YDIM + lane]);
        if (lane == 0)
            atomicAdd(counts + l, 1.0f);
    }
}

// Pass 2: one wave per label.
//  res = seg_a[l]/denom; logits = res @ w2 + b2 (50 lanes, coalesced w2 reads);
//  prediction = softmax(logits); logp = log_softmax(prediction);
//  loss_l = -sum_j ymean_j * logp_j ; atomicAdd(out, loss_l / L)
__global__ __launch_bounds__(64) void wlp_finalize(
    const float* __restrict__ seg_a, const float* __restrict__ ysum,
    const float* __restrict__ counts, const float* __restrict__ w2,
    const float* __restrict__ b2, float* __restrict__ out)
{
    const int l = blockIdx.x;
    const int j = threadIdx.x;  // 0..63, lanes >= YDIM are passive in reduces

    __shared__ float res[DIM];
    const float inv_denom = 1.0f / fmaxf(counts[l], 1.0f);
    for (int d = j; d < DIM; d += 64)
        res[d] = seg_a[(size_t)l * DIM + d] * inv_denom;
    __syncthreads();

    const float NEG = -3.402823466e38f;
    float logit = NEG;
    if (j < YDIM) {
        float acc = b2[j];
        #pragma unroll 8
        for (int d = 0; d < DIM; ++d) acc += res[d] * w2[d * YDIM + j];
        logit = acc;
    }

    // softmax(logits)
    float m = logit;
    #pragma unroll
    for (int off = 32; off > 0; off >>= 1) m = fmaxf(m, __shfl_xor(m, off));
    float e = (j < YDIM) ? __expf(logit - m) : 0.0f;
    float s = e;
    #pragma unroll
    for (int off = 32; off > 0; off >>= 1) s += __shfl_xor(s, off);
    const float p = e / s;  // prediction (valid for j < YDIM)

    // log_softmax(prediction)  [faithful double softmax]
    float pm = (j < YDIM) ? p : NEG;
    float m2 = pm;
    #pragma unroll
    for (int off = 32; off > 0; off >>= 1) m2 = fmaxf(m2, __shfl_xor(m2, off));
    float e2 = (j < YDIM) ? __expf(p - m2) : 0.0f;
    float s2 = e2;
    #pragma unroll
    for (int off = 32; off > 0; off >>= 1) s2 += __shfl_xor(s2, off);
    const float logp = p - m2 - __logf(s2);

    float contrib = (j < YDIM) ? ysum[(size_t)l * YDIM + j] * inv_denom * logp
                               : 0.0f;
    #pragma unroll
    for (int off = 32; off > 0; off >>= 1) contrib += __shfl_xor(contrib, off);
    if (j == 0) atomicAdd(out, -contrib / (float)NLAB);
}

extern "C" void kernel_launch(void* const* d_in, const int* in_sizes, int n_in,
                              void* d_out, int out_size, void* d_ws, size_t ws_size,
                              hipStream_t stream) {
    const float* x      = (const float*)d_in[0];
    const int*   labels = (const int*)  d_in[1];
    const float* y      = (const float*)d_in[2];
    const float* w1     = (const float*)d_in[3];
    const float* b1     = (const float*)d_in[4];
    const float* w2     = (const float*)d_in[5];
    const float* b2     = (const float*)d_in[6];
    float* out = (float*)d_out;

    float* seg_a  = (float*)d_ws;                 // [NLAB, DIM]
    float* ysum   = seg_a + (size_t)NLAB * DIM;   // [NLAB, YDIM]
    float* counts = ysum + (size_t)NLAB * YDIM;   // [NLAB]
    const size_t ws_needed =
        ((size_t)NLAB * DIM + (size_t)NLAB * YDIM + NLAB) * sizeof(float);

    hipMemsetAsync(d_ws, 0, ws_needed, stream);
    hipMemsetAsync(d_out, 0, sizeof(float), stream);

    wlp_accum<<<2048, 256, 0, stream>>>(x, labels, y, w1, b1,
                                        seg_a, ysum, counts);
    wlp_finalize<<<NLAB, 64, 0, stream>>>(seg_a, ysum, counts, w2, b2, out);
}

// Round 2
// 318.991 us; speedup vs baseline: 5.9600x; 5.9600x over previous
//
#include <hip/hip_runtime.h>
#include <math.h>

#define NROWS 500000
#define DIM 256
#define YDIM 50
#define NLAB 1000

// ---------- Pass 1: label histogram (LDS-privatized) ----------
__global__ __launch_bounds__(256) void k_hist(const int* __restrict__ labels,
                                              int* __restrict__ hist) {
    __shared__ int lh[NLAB];
    for (int i = threadIdx.x; i < NLAB; i += 256) lh[i] = 0;
    __syncthreads();
    for (int i = blockIdx.x * 256 + threadIdx.x; i < NROWS; i += gridDim.x * 256)
        atomicAdd(&lh[labels[i]], 1);
    __syncthreads();
    for (int i = threadIdx.x; i < NLAB; i += 256) {
        int v = lh[i];
        if (v) atomicAdd(&hist[i], v);
    }
}

// ---------- Pass 2: exclusive scan over 1000 bins (single block) ----------
__global__ __launch_bounds__(1024) void k_scan(const int* __restrict__ hist,
                                               int* __restrict__ offsets,
                                               int* __restrict__ cursor) {
    __shared__ int tmp[NLAB];
    const int t = threadIdx.x;
    int v = 0;
    if (t < NLAB) { v = hist[t]; tmp[t] = v; }
    __syncthreads();
    for (int off = 1; off < NLAB; off <<= 1) {
        int add = 0;
        if (t < NLAB && t >= off) add = tmp[t - off];
        __syncthreads();
        if (t < NLAB) tmp[t] += add;
        __syncthreads();
    }
    if (t < NLAB) {
        int excl = tmp[t] - v;   // exclusive prefix
        offsets[t] = excl;
        cursor[t]  = excl;
    }
    if (t == 0) offsets[NLAB] = NROWS;
}

// ---------- Pass 3: scatter row indices into label-sorted order ----------
__global__ __launch_bounds__(256) void k_scatter(const int* __restrict__ labels,
                                                 int* __restrict__ cursor,
                                                 int* __restrict__ order) {
    for (int i = blockIdx.x * 256 + threadIdx.x; i < NROWS; i += gridDim.x * 256) {
        const int l = labels[i];
        const int pos = atomicAdd(&cursor[l], 1);
        order[pos] = i;
    }
}

// ---------- Pass 4: per-label accumulate (registers) + finalize ----------
// One block (4 waves) per label. Each wave handles rows [start+wib :: 4].
__global__ __launch_bounds__(256) void k_accum_finalize(
    const float* __restrict__ x, const float* __restrict__ y,
    const int* __restrict__ order, const int* __restrict__ offsets,
    const float* __restrict__ w1, const float* __restrict__ b1,
    const float* __restrict__ w2, const float* __restrict__ b2,
    float* __restrict__ out)
{
    const int l    = blockIdx.x;
    const int tid  = threadIdx.x;
    const int lane = tid & 63;
    const int wib  = tid >> 6;

    const int start = offsets[l];
    const int end   = offsets[l + 1];
    const int cnt   = end - start;

    const float4 wv  = reinterpret_cast<const float4*>(w1)[lane];
    const float  b1v = b1[0];

    float4 acc  = make_float4(0.f, 0.f, 0.f, 0.f);
    float  yacc = 0.f;

    // software-prefetch the next row index to hide the dependent load
    int r = start + wib;
    int i_next = (r < end) ? order[r] : 0;
    for (; r < end; r += 4) {
        const int i = i_next;
        const int rn = r + 4;
        if (rn < end) i_next = order[rn];

        const float4 xv = reinterpret_cast<const float4*>(x)[i * 64 + lane];
        float p = xv.x * wv.x + xv.y * wv.y + xv.z * wv.z + xv.w * wv.w;
        #pragma unroll
        for (int off = 32; off > 0; off >>= 1) p += __shfl_xor(p, off);
        const float g = 1.0f / (1.0f + __expf(-(p + b1v)));

        acc.x += g * xv.x; acc.y += g * xv.y;
        acc.z += g * xv.z; acc.w += g * xv.w;
        if (lane < YDIM) yacc += y[(size_t)i * YDIM + lane];
    }

    // cross-wave reduction in LDS
    __shared__ float sacc[4][DIM];     // 4 KB
    __shared__ float syacc[4][64];     // 1 KB
    reinterpret_cast<float4*>(sacc[wib])[lane] = acc;
    syacc[wib][lane] = yacc;
    __syncthreads();

    __shared__ float res[DIM];
    __shared__ float ymean[YDIM];
    const float inv_denom = 1.0f / fmaxf((float)cnt, 1.0f);
    for (int d = tid; d < DIM; d += 256)
        res[d] = (sacc[0][d] + sacc[1][d] + sacc[2][d] + sacc[3][d]) * inv_denom;
    if (tid < YDIM)
        ymean[tid] = (syacc[0][tid] + syacc[1][tid] + syacc[2][tid] + syacc[3][tid])
                     * inv_denom;
    __syncthreads();

    if (wib == 0) {
        const float NEG = -3.402823466e38f;
        float logit = NEG;
        if (lane < YDIM) {
            float a = b2[lane];
            #pragma unroll 8
            for (int d = 0; d < DIM; ++d) a += res[d] * w2[d * YDIM + lane];
            logit = a;
        }
        // softmax(logits)
        float m = logit;
        #pragma unroll
        for (int off = 32; off > 0; off >>= 1) m = fmaxf(m, __shfl_xor(m, off));
        float e = (lane < YDIM) ? __expf(logit - m) : 0.0f;
        float s = e;
        #pragma unroll
        for (int off = 32; off > 0; off >>= 1) s += __shfl_xor(s, off);
        const float p = e / s;

        // log_softmax(prediction) — faithful double softmax
        float pm = (lane < YDIM) ? p : NEG;
        float m2 = pm;
        #pragma unroll
        for (int off = 32; off > 0; off >>= 1) m2 = fmaxf(m2, __shfl_xor(m2, off));
        float e2 = (lane < YDIM) ? __expf(p - m2) : 0.0f;
        float s2 = e2;
        #pragma unroll
        for (int off = 32; off > 0; off >>= 1) s2 += __shfl_xor(s2, off);
        const float logp = p - m2 - __logf(s2);

        float contrib = (lane < YDIM) ? ymean[lane] * logp : 0.0f;
        #pragma unroll
        for (int off = 32; off > 0; off >>= 1) contrib += __shfl_xor(contrib, off);
        if (lane == 0) atomicAdd(out, -contrib / (float)NLAB);
    }
}

extern "C" void kernel_launch(void* const* d_in, const int* in_sizes, int n_in,
                              void* d_out, int out_size, void* d_ws, size_t ws_size,
                              hipStream_t stream) {
    const float* x      = (const float*)d_in[0];
    const int*   labels = (const int*)  d_in[1];
    const float* y      = (const float*)d_in[2];
    const float* w1     = (const float*)d_in[3];
    const float* b1     = (const float*)d_in[4];
    const float* w2     = (const float*)d_in[5];
    const float* b2     = (const float*)d_in[6];
    float* out = (float*)d_out;

    // workspace layout (ints): hist[NLAB] | offsets[NLAB+1] | cursor[NLAB] | order[NROWS]
    int* hist    = (int*)d_ws;
    int* offsets = hist + NLAB;
    int* cursor  = offsets + NLAB + 1;
    int* order   = cursor + NLAB;

    hipMemsetAsync(hist, 0, NLAB * sizeof(int), stream);
    hipMemsetAsync(d_out, 0, sizeof(float), stream);

    k_hist<<<256, 256, 0, stream>>>(labels, hist);
    k_scan<<<1, 1024, 0, stream>>>(hist, offsets, cursor);
    k_scatter<<<512, 256, 0, stream>>>(labels, cursor, order);
    k_accum_finalize<<<NLAB, 256, 0, stream>>>(x, y, order, offsets,
                                               w1, b1, w2, b2, out);
}

// Round 3
// 247.524 us; speedup vs baseline: 7.6809x; 1.2887x over previous
//
#include <hip/hip_runtime.h>
#include <math.h>

#define NROWS 500000
#define DIM 256
#define YDIM 50
#define NLAB 1000

// ---------- Pass 1: label histogram (LDS-privatized) ----------
__global__ __launch_bounds__(256) void k_hist(const int* __restrict__ labels,
                                              int* __restrict__ hist) {
    __shared__ int lh[NLAB];
    for (int i = threadIdx.x; i < NLAB; i += 256) lh[i] = 0;
    __syncthreads();
    for (int i = blockIdx.x * 256 + threadIdx.x; i < NROWS; i += gridDim.x * 256)
        atomicAdd(&lh[labels[i]], 1);
    __syncthreads();
    for (int i = threadIdx.x; i < NLAB; i += 256) {
        int v = lh[i];
        if (v) atomicAdd(&hist[i], v);
    }
}

// ---------- Pass 2: exclusive scan over 1000 bins (single block) ----------
__global__ __launch_bounds__(1024) void k_scan(const int* __restrict__ hist,
                                               int* __restrict__ offsets,
                                               int* __restrict__ cursor) {
    __shared__ int tmp[NLAB];
    const int t = threadIdx.x;
    int v = 0;
    if (t < NLAB) { v = hist[t]; tmp[t] = v; }
    __syncthreads();
    for (int off = 1; off < NLAB; off <<= 1) {
        int add = 0;
        if (t < NLAB && t >= off) add = tmp[t - off];
        __syncthreads();
        if (t < NLAB) tmp[t] += add;
        __syncthreads();
    }
    if (t < NLAB) {
        int excl = tmp[t] - v;
        offsets[t] = excl;
        cursor[t]  = excl;
    }
    if (t == 0) offsets[NLAB] = NROWS;
}

// ---------- Pass 3: scatter row indices into label-sorted order ----------
__global__ __launch_bounds__(256) void k_scatter(const int* __restrict__ labels,
                                                 int* __restrict__ cursor,
                                                 int* __restrict__ order) {
    for (int i = blockIdx.x * 256 + threadIdx.x; i < NROWS; i += gridDim.x * 256) {
        const int l = labels[i];
        const int pos = atomicAdd(&cursor[l], 1);
        order[pos] = i;
    }
}

// ---------- Pass 4: per-label accumulate (4-row ILP) + finalize ----------
// One block (4 waves) per label. Wave wib owns row groups
// [start+4*wib .. start+4*wib+3], stride 16. Exactly one wave gets the
// partial tail group, handled by the single-row tail loop.
__global__ __launch_bounds__(256) void k_accum_finalize(
    const float* __restrict__ x, const float* __restrict__ y,
    const int* __restrict__ order, const int* __restrict__ offsets,
    const float* __restrict__ w1, const float* __restrict__ b1,
    const float* __restrict__ w2, const float* __restrict__ b2,
    float* __restrict__ out)
{
    const int l    = blockIdx.x;
    const int tid  = threadIdx.x;
    const int lane = tid & 63;
    const int wib  = tid >> 6;

    const int start = offsets[l];
    const int end   = offsets[l + 1];
    const int cnt   = end - start;

    const float4* __restrict__ X = reinterpret_cast<const float4*>(x);
    const float4 wv  = reinterpret_cast<const float4*>(w1)[lane];
    const float  b1v = b1[0];
    const bool   yl  = lane < YDIM;

    float4 acc  = make_float4(0.f, 0.f, 0.f, 0.f);
    float  yacc = 0.f;

    int r = start + wib * 4;
    for (; r + 4 <= end; r += 16) {
        const int i0 = order[r];
        const int i1 = order[r + 1];
        const int i2 = order[r + 2];
        const int i3 = order[r + 3];

        const float4 x0 = X[(size_t)i0 * 64 + lane];
        const float4 x1 = X[(size_t)i1 * 64 + lane];
        const float4 x2 = X[(size_t)i2 * 64 + lane];
        const float4 x3 = X[(size_t)i3 * 64 + lane];

        float y0 = 0.f, y1 = 0.f, y2 = 0.f, y3 = 0.f;
        if (yl) {
            y0 = y[(size_t)i0 * YDIM + lane];
            y1 = y[(size_t)i1 * YDIM + lane];
            y2 = y[(size_t)i2 * YDIM + lane];
            y3 = y[(size_t)i3 * YDIM + lane];
        }

        float p0 = x0.x * wv.x + x0.y * wv.y + x0.z * wv.z + x0.w * wv.w;
        float p1 = x1.x * wv.x + x1.y * wv.y + x1.z * wv.z + x1.w * wv.w;
        float p2 = x2.x * wv.x + x2.y * wv.y + x2.z * wv.z + x2.w * wv.w;
        float p3 = x3.x * wv.x + x3.y * wv.y + x3.z * wv.z + x3.w * wv.w;

        #pragma unroll
        for (int off = 32; off > 0; off >>= 1) {
            p0 += __shfl_xor(p0, off);
            p1 += __shfl_xor(p1, off);
            p2 += __shfl_xor(p2, off);
            p3 += __shfl_xor(p3, off);
        }

        const float g0 = 1.0f / (1.0f + __expf(-(p0 + b1v)));
        const float g1 = 1.0f / (1.0f + __expf(-(p1 + b1v)));
        const float g2 = 1.0f / (1.0f + __expf(-(p2 + b1v)));
        const float g3 = 1.0f / (1.0f + __expf(-(p3 + b1v)));

        acc.x += g0 * x0.x + g1 * x1.x + g2 * x2.x + g3 * x3.x;
        acc.y += g0 * x0.y + g1 * x1.y + g2 * x2.y + g3 * x3.y;
        acc.z += g0 * x0.z + g1 * x1.z + g2 * x2.z + g3 * x3.z;
        acc.w += g0 * x0.w + g1 * x1.w + g2 * x2.w + g3 * x3.w;
        yacc  += (y0 + y1) + (y2 + y3);
    }
    // tail (only one wave enters; 1-3 rows)
    for (; r < end; ++r) {
        const int i = order[r];
        const float4 xv = X[(size_t)i * 64 + lane];
        float p = xv.x * wv.x + xv.y * wv.y + xv.z * wv.z + xv.w * wv.w;
        #pragma unroll
        for (int off = 32; off > 0; off >>= 1) p += __shfl_xor(p, off);
        const float g = 1.0f / (1.0f + __expf(-(p + b1v)));
        acc.x += g * xv.x; acc.y += g * xv.y;
        acc.z += g * xv.z; acc.w += g * xv.w;
        if (yl) yacc += y[(size_t)i * YDIM + lane];
    }

    // cross-wave reduction in LDS
    __shared__ float sacc[4][DIM];
    __shared__ float syacc[4][64];
    reinterpret_cast<float4*>(sacc[wib])[lane] = acc;
    syacc[wib][lane] = yacc;
    __syncthreads();

    __shared__ float res[DIM];
    __shared__ float ymean[YDIM];
    const float inv_denom = 1.0f / fmaxf((float)cnt, 1.0f);
    for (int d = tid; d < DIM; d += 256)
        res[d] = (sacc[0][d] + sacc[1][d] + sacc[2][d] + sacc[3][d]) * inv_denom;
    if (tid < YDIM)
        ymean[tid] = (syacc[0][tid] + syacc[1][tid] + syacc[2][tid] + syacc[3][tid])
                     * inv_denom;
    __syncthreads();

    if (wib == 0) {
        const float NEG = -3.402823466e38f;
        float logit = NEG;
        if (lane < YDIM) {
            float a = b2[lane];
            #pragma unroll 8
            for (int d = 0; d < DIM; ++d) a += res[d] * w2[d * YDIM + lane];
            logit = a;
        }
        float m = logit;
        #pragma unroll
        for (int off = 32; off > 0; off >>= 1) m = fmaxf(m, __shfl_xor(m, off));
        float e = (lane < YDIM) ? __expf(logit - m) : 0.0f;
        float s = e;
        #pragma unroll
        for (int off = 32; off > 0; off >>= 1) s += __shfl_xor(s, off);
        const float p = e / s;

        float pm = (lane < YDIM) ? p : NEG;
        float m2 = pm;
        #pragma unroll
        for (int off = 32; off > 0; off >>= 1) m2 = fmaxf(m2, __shfl_xor(m2, off));
        float e2 = (lane < YDIM) ? __expf(p - m2) : 0.0f;
        float s2 = e2;
        #pragma unroll
        for (int off = 32; off > 0; off >>= 1) s2 += __shfl_xor(s2, off);
        const float logp = p - m2 - __logf(s2);

        float contrib = (lane < YDIM) ? ymean[lane] * logp : 0.0f;
        #pragma unroll
        for (int off = 32; off > 0; off >>= 1) contrib += __shfl_xor(contrib, off);
        if (lane == 0) atomicAdd(out, -contrib / (float)NLAB);
    }
}

extern "C" void kernel_launch(void* const* d_in, const int* in_sizes, int n_in,
                              void* d_out, int out_size, void* d_ws, size_t ws_size,
                              hipStream_t stream) {
    const float* x      = (const float*)d_in[0];
    const int*   labels = (const int*)  d_in[1];
    const float* y      = (const float*)d_in[2];
    const float* w1     = (const float*)d_in[3];
    const float* b1     = (const float*)d_in[4];
    const float* w2     = (const float*)d_in[5];
    const float* b2     = (const float*)d_in[6];
    float* out = (float*)d_out;

    // workspace (ints): hist[NLAB] | offsets[NLAB+1] | cursor[NLAB] | order[NROWS]
    int* hist    = (int*)d_ws;
    int* offsets = hist + NLAB;
    int* cursor  = offsets + NLAB + 1;
    int* order   = cursor + NLAB;

    hipMemsetAsync(hist, 0, NLAB * sizeof(int), stream);
    hipMemsetAsync(d_out, 0, sizeof(float), stream);

    k_hist<<<256, 256, 0, stream>>>(labels, hist);
    k_scan<<<1, 1024, 0, stream>>>(hist, offsets, cursor);
    k_scatter<<<512, 256, 0, stream>>>(labels, cursor, order);
    k_accum_finalize<<<NLAB, 256, 0, stream>>>(x, y, order, offsets,
                                               w1, b1, w2, b2, out);
}

// Round 4
// 243.075 us; speedup vs baseline: 7.8214x; 1.0183x over previous
//
#include <hip/hip_runtime.h>
#include <math.h>

#define NROWS 500000
#define DIM 256
#define YDIM 50
#define NLAB 1000
#define WPB 8          // waves per block in the main kernel

// ---------- Pass 1: label histogram (LDS-privatized) ----------
__global__ __launch_bounds__(256) void k_hist(const int* __restrict__ labels,
                                              int* __restrict__ hist) {
    __shared__ int lh[NLAB];
    for (int i = threadIdx.x; i < NLAB; i += 256) lh[i] = 0;
    __syncthreads();
    for (int i = blockIdx.x * 256 + threadIdx.x; i < NROWS; i += gridDim.x * 256)
        atomicAdd(&lh[labels[i]], 1);
    __syncthreads();
    for (int i = threadIdx.x; i < NLAB; i += 256) {
        int v = lh[i];
        if (v) atomicAdd(&hist[i], v);
    }
}

// ---------- Pass 2: exclusive scan over 1000 bins (single block) ----------
__global__ __launch_bounds__(1024) void k_scan(const int* __restrict__ hist,
                                               int* __restrict__ offsets,
                                               int* __restrict__ cursor,
                                               float* __restrict__ out) {
    __shared__ int tmp[NLAB];
    const int t = threadIdx.x;
    int v = 0;
    if (t < NLAB) { v = hist[t]; tmp[t] = v; }
    __syncthreads();
    for (int off = 1; off < NLAB; off <<= 1) {
        int add = 0;
        if (t < NLAB && t >= off) add = tmp[t - off];
        __syncthreads();
        if (t < NLAB) tmp[t] += add;
        __syncthreads();
    }
    if (t < NLAB) {
        int excl = tmp[t] - v;
        offsets[t] = excl;
        cursor[t]  = excl;
    }
    if (t == 0) { offsets[NLAB] = NROWS; out[0] = 0.0f; }
}

// ---------- Pass 3: scatter row indices into label-sorted order ----------
__global__ __launch_bounds__(256) void k_scatter(const int* __restrict__ labels,
                                                 int* __restrict__ cursor,
                                                 int* __restrict__ order) {
    for (int i = blockIdx.x * 256 + threadIdx.x; i < NROWS; i += gridDim.x * 256) {
        const int l = labels[i];
        const int pos = atomicAdd(&cursor[l], 1);
        order[pos] = i;
    }
}

// ---------- Pass 4: per-label accumulate (8 waves, 4-row groups, index
// prefetch) + finalize. Wave wib owns groups at offset wib*4, stride WPB*4.
__global__ __launch_bounds__(512, 4) void k_accum_finalize(
    const float* __restrict__ x, const float* __restrict__ y,
    const int* __restrict__ order, const int* __restrict__ offsets,
    const float* __restrict__ w1, const float* __restrict__ b1,
    const float* __restrict__ w2, const float* __restrict__ b2,
    float* __restrict__ out)
{
    const int l    = blockIdx.x;
    const int tid  = threadIdx.x;
    const int lane = tid & 63;
    const int wib  = tid >> 6;

    const int start = offsets[l];
    const int end   = offsets[l + 1];
    const int cnt   = end - start;

    const float4* __restrict__ X = reinterpret_cast<const float4*>(x);
    const float4 wv  = reinterpret_cast<const float4*>(w1)[lane];
    const float  b1v = b1[0];
    const bool   yl  = lane < YDIM;

    float4 acc  = make_float4(0.f, 0.f, 0.f, 0.f);
    float  yacc = 0.f;

    int r = start + wib * 4;
    int i0, i1, i2, i3;
    if (r + 4 <= end) { i0 = order[r]; i1 = order[r+1]; i2 = order[r+2]; i3 = order[r+3]; }
    for (; r + 4 <= end; ) {
        const int rn = r + WPB * 4;
        // current group's gathers, issued ASAP
        const float4 x0 = X[(size_t)i0 * 64 + lane];
        const float4 x1 = X[(size_t)i1 * 64 + lane];
        const float4 x2 = X[(size_t)i2 * 64 + lane];
        const float4 x3 = X[(size_t)i3 * 64 + lane];
        float y0 = 0.f, y1 = 0.f, y2 = 0.f, y3 = 0.f;
        if (yl) {
            y0 = y[(size_t)i0 * YDIM + lane];
            y1 = y[(size_t)i1 * YDIM + lane];
            y2 = y[(size_t)i2 * YDIM + lane];
            y3 = y[(size_t)i3 * YDIM + lane];
        }
        // prefetch next group's indices (overlaps with compute below)
        if (rn + 4 <= end) {
            i0 = order[rn]; i1 = order[rn+1]; i2 = order[rn+2]; i3 = order[rn+3];
        }

        float p0 = x0.x * wv.x + x0.y * wv.y + x0.z * wv.z + x0.w * wv.w;
        float p1 = x1.x * wv.x + x1.y * wv.y + x1.z * wv.z + x1.w * wv.w;
        float p2 = x2.x * wv.x + x2.y * wv.y + x2.z * wv.z + x2.w * wv.w;
        float p3 = x3.x * wv.x + x3.y * wv.y + x3.z * wv.z + x3.w * wv.w;

        #pragma unroll
        for (int off = 32; off > 0; off >>= 1) {
            p0 += __shfl_xor(p0, off);
            p1 += __shfl_xor(p1, off);
            p2 += __shfl_xor(p2, off);
            p3 += __shfl_xor(p3, off);
        }

        const float g0 = 1.0f / (1.0f + __expf(-(p0 + b1v)));
        const float g1 = 1.0f / (1.0f + __expf(-(p1 + b1v)));
        const float g2 = 1.0f / (1.0f + __expf(-(p2 + b1v)));
        const float g3 = 1.0f / (1.0f + __expf(-(p3 + b1v)));

        acc.x += g0 * x0.x + g1 * x1.x + g2 * x2.x + g3 * x3.x;
        acc.y += g0 * x0.y + g1 * x1.y + g2 * x2.y + g3 * x3.y;
        acc.z += g0 * x0.z + g1 * x1.z + g2 * x2.z + g3 * x3.z;
        acc.w += g0 * x0.w + g1 * x1.w + g2 * x2.w + g3 * x3.w;
        yacc  += (y0 + y1) + (y2 + y3);
        r = rn;
    }
    // tail: the one wave whose group straddles end handles 1-3 rows
    for (; r < end; ++r) {
        const int i = order[r];
        const float4 xv = X[(size_t)i * 64 + lane];
        float p = xv.x * wv.x + xv.y * wv.y + xv.z * wv.z + xv.w * wv.w;
        #pragma unroll
        for (int off = 32; off > 0; off >>= 1) p += __shfl_xor(p, off);
        const float g = 1.0f / (1.0f + __expf(-(p + b1v)));
        acc.x += g * xv.x; acc.y += g * xv.y;
        acc.z += g * xv.z; acc.w += g * xv.w;
        if (yl) yacc += y[(size_t)i * YDIM + lane];
    }

    // cross-wave reduction in LDS
    __shared__ float sacc[WPB][DIM];
    __shared__ float syacc[WPB][64];
    reinterpret_cast<float4*>(sacc[wib])[lane] = acc;
    syacc[wib][lane] = yacc;
    __syncthreads();

    __shared__ float res[DIM];
    __shared__ float ymean[YDIM];
    const float inv_denom = 1.0f / fmaxf((float)cnt, 1.0f);
    for (int d = tid; d < DIM; d += 512) {
        float s = 0.f;
        #pragma unroll
        for (int w = 0; w < WPB; ++w) s += sacc[w][d];
        res[d] = s * inv_denom;
    }
    if (tid < YDIM) {
        float s = 0.f;
        #pragma unroll
        for (int w = 0; w < WPB; ++w) s += syacc[w][tid];
        ymean[tid] = s * inv_denom;
    }
    __syncthreads();

    if (wib == 0) {
        const float NEG = -3.402823466e38f;
        float logit = NEG;
        if (lane < YDIM) {
            float a = b2[lane];
            #pragma unroll 8
            for (int d = 0; d < DIM; ++d) a += res[d] * w2[d * YDIM + lane];
            logit = a;
        }
        float m = logit;
        #pragma unroll
        for (int off = 32; off > 0; off >>= 1) m = fmaxf(m, __shfl_xor(m, off));
        float e = (lane < YDIM) ? __expf(logit - m) : 0.0f;
        float s = e;
        #pragma unroll
        for (int off = 32; off > 0; off >>= 1) s += __shfl_xor(s, off);
        const float p = e / s;

        float pm = (lane < YDIM) ? p : NEG;
        float m2 = pm;
        #pragma unroll
        for (int off = 32; off > 0; off >>= 1) m2 = fmaxf(m2, __shfl_xor(m2, off));
        float e2 = (lane < YDIM) ? __expf(p - m2) : 0.0f;
        float s2 = e2;
        #pragma unroll
        for (int off = 32; off > 0; off >>= 1) s2 += __shfl_xor(s2, off);
        const float logp = p - m2 - __logf(s2);

        float contrib = (lane < YDIM) ? ymean[lane] * logp : 0.0f;
        #pragma unroll
        for (int off = 32; off > 0; off >>= 1) contrib += __shfl_xor(contrib, off);
        if (lane == 0) atomicAdd(out, -contrib / (float)NLAB);
    }
}

extern "C" void kernel_launch(void* const* d_in, const int* in_sizes, int n_in,
                              void* d_out, int out_size, void* d_ws, size_t ws_size,
                              hipStream_t stream) {
    const float* x      = (const float*)d_in[0];
    const int*   labels = (const int*)  d_in[1];
    const float* y      = (const float*)d_in[2];
    const float* w1     = (const float*)d_in[3];
    const float* b1     = (const float*)d_in[4];
    const float* w2     = (const float*)d_in[5];
    const float* b2     = (const float*)d_in[6];
    float* out = (float*)d_out;

    // workspace (ints): hist[NLAB] | offsets[NLAB+1] | cursor[NLAB] | order[NROWS]
    int* hist    = (int*)d_ws;
    int* offsets = hist + NLAB;
    int* cursor  = offsets + NLAB + 1;
    int* order   = cursor + NLAB;

    hipMemsetAsync(hist, 0, NLAB * sizeof(int), stream);

    k_hist<<<256, 256, 0, stream>>>(labels, hist);
    k_scan<<<1, 1024, 0, stream>>>(hist, offsets, cursor, out);
    k_scatter<<<512, 256, 0, stream>>>(labels, cursor, order);
    k_accum_finalize<<<NLAB, 512, 0, stream>>>(x, y, order, offsets,
                                               w1, b1, w2, b2, out);
}